// Round 3
// baseline (223.257 us; speedup 1.0000x reference)
//
#include <hip/hip_runtime.h>
#include <math.h>

// Problem constants
#define NB 16
#define NL 128
#define DIN 512
#define NH 256
#define NTAGS 45
#define NM (NB*NL)          // 2048 rows
#define NJ (NL+1)           // 129 arc columns

// ws layout (floats)
#define HID_OFF   0
#define U_OFF     (NM*NH)                 // 524288
#define HV_OFF    (U_OFF + NM*NH)         // 1048576
#define VROOT_OFF (HV_OFF + NM*NH)        // 1572864
#define ACC_OFF   (VROOT_OFF + NH)        // 1573120

// ---------------------------------------------------------------------------
// Kernel 1: hidden = relu(C @ W1 + b1)   (2048x512)@(512x256)
// tile 32(M) x 64(N), BK=16, 256 threads, 2x4/thread -> 256 blocks.
// Block (0,0) also zeroes the loss accumulator (ws is poisoned each call).
// ---------------------------------------------------------------------------
__global__ __launch_bounds__(256) void gemm_hidden(
    const float* __restrict__ A,   // 2048 x 512
    const float* __restrict__ W,   // 512 x 256
    const float* __restrict__ bias,// 256
    float* __restrict__ out,       // 2048 x 256
    float* __restrict__ accum)
{
    const int K = DIN, N = NH;
    __shared__ float As[16][34];
    __shared__ float Bs[16][68];
    int m0 = blockIdx.x * 32;
    int n0 = blockIdx.y * 64;
    int tid = threadIdx.x;
    if (blockIdx.x == 0 && blockIdx.y == 0 && tid == 0) accum[0] = 0.f;
    int tm = tid >> 4, tn = tid & 15;
    int lm = tid >> 2, lk = (tid & 3) * 4;
    int bk = tid >> 4, bn = (tid & 15) * 4;
    float acc[2][4] = {{0.f}};

    for (int k0 = 0; k0 < K; k0 += 16) {
        if (tid < 128) {
            float4 a4 = *(const float4*)&A[(m0 + lm) * K + k0 + lk];
            As[lk + 0][lm] = a4.x; As[lk + 1][lm] = a4.y;
            As[lk + 2][lm] = a4.z; As[lk + 3][lm] = a4.w;
        }
        float4 b4 = *(const float4*)&W[(k0 + bk) * N + n0 + bn];
        *(float4*)&Bs[bk][bn] = b4;
        __syncthreads();
        #pragma unroll
        for (int kk = 0; kk < 16; kk++) {
            float2 a2 = *(const float2*)&As[kk][tm * 2];
            float4 bv = *(const float4*)&Bs[kk][tn * 4];
            float ar[2] = {a2.x, a2.y};
            float br[4] = {bv.x, bv.y, bv.z, bv.w};
            #pragma unroll
            for (int r = 0; r < 2; r++)
                #pragma unroll
                for (int c = 0; c < 4; c++)
                    acc[r][c] += ar[r] * br[c];
        }
        __syncthreads();
    }
    int col = n0 + tn * 4;
    float4 bb = *(const float4*)&bias[col];
    #pragma unroll
    for (int r = 0; r < 2; r++) {
        int row = m0 + tm * 2 + r;
        float4 o;
        o.x = fmaxf(acc[r][0] + bb.x, 0.f);
        o.y = fmaxf(acc[r][1] + bb.y, 0.f);
        o.z = fmaxf(acc[r][2] + bb.z, 0.f);
        o.w = fmaxf(acc[r][3] + bb.w, 0.f);
        *(float4*)&out[row * N + col] = o;
    }
}

// ---------------------------------------------------------------------------
// Kernel 2: u = hidden@Wa + bp ; hv = hidden@Wb ; vroot = root@Wb
// GEMM M=2048, N=512, K=256; tile 32x64 -> grid (65, 8); blockIdx.x==64
// computes the root row (k-parallel, 4 partials reduced in LDS).
// ---------------------------------------------------------------------------
__global__ __launch_bounds__(256) void gemm_uv(
    const float* __restrict__ hidden, // 2048 x 256
    const float* __restrict__ Wp,     // 512 x 256
    const float* __restrict__ bp,     // 256
    const float* __restrict__ root,   // 256
    float* __restrict__ u,            // 2048 x 256
    float* __restrict__ hv,           // 2048 x 256
    float* __restrict__ vroot)        // 256
{
    const int K = NH;
    __shared__ float As[16][34];
    __shared__ float Bs[16][68];
    __shared__ float part[4][64];
    int n0 = blockIdx.y * 64;
    int tid = threadIdx.x;

    if (blockIdx.x == 64) {            // root row block
        if (n0 < NH) return;
        int col = (n0 - NH) + (tid & 63);
        int kc = tid >> 6;
        float p = 0.f;
        #pragma unroll 8
        for (int c = kc * 64; c < kc * 64 + 64; c++)
            p += root[c] * Wp[(NH + c) * NH + col];
        part[kc][tid & 63] = p;
        __syncthreads();
        if (tid < 64)
            vroot[(n0 - NH) + tid] = part[0][tid] + part[1][tid]
                                   + part[2][tid] + part[3][tid];
        return;
    }

    int m0 = blockIdx.x * 32;
    bool isU = (n0 < NH);
    int tm = tid >> 4, tn = tid & 15;
    int lm = tid >> 2, lk = (tid & 3) * 4;
    int bk = tid >> 4, bn = (tid & 15) * 4;
    float acc[2][4] = {{0.f}};

    for (int k0 = 0; k0 < K; k0 += 16) {
        if (tid < 128) {
            float4 a4 = *(const float4*)&hidden[(m0 + lm) * K + k0 + lk];
            As[lk + 0][lm] = a4.x; As[lk + 1][lm] = a4.y;
            As[lk + 2][lm] = a4.z; As[lk + 3][lm] = a4.w;
        }
        int c = k0 + bk;
        float4 b4;
        if (isU) b4 = *(const float4*)&Wp[c * NH + n0 + bn];
        else     b4 = *(const float4*)&Wp[(NH + c) * NH + (n0 - NH) + bn];
        *(float4*)&Bs[bk][bn] = b4;
        __syncthreads();
        #pragma unroll
        for (int kk = 0; kk < 16; kk++) {
            float2 a2 = *(const float2*)&As[kk][tm * 2];
            float4 bv = *(const float4*)&Bs[kk][tn * 4];
            float ar[2] = {a2.x, a2.y};
            float br[4] = {bv.x, bv.y, bv.z, bv.w};
            #pragma unroll
            for (int r = 0; r < 2; r++)
                #pragma unroll
                for (int cc = 0; cc < 4; cc++)
                    acc[r][cc] += ar[r] * br[cc];
        }
        __syncthreads();
    }
    if (isU) {
        int col = n0 + tn * 4;
        float4 bb = *(const float4*)&bp[col];
        #pragma unroll
        for (int r = 0; r < 2; r++) {
            int row = m0 + tm * 2 + r;
            float4 o;
            o.x = acc[r][0] + bb.x; o.y = acc[r][1] + bb.y;
            o.z = acc[r][2] + bb.z; o.w = acc[r][3] + bb.w;
            *(float4*)&u[row * NH + col] = o;
        }
    } else {
        int col = (n0 - NH) + tn * 4;
        #pragma unroll
        for (int r = 0; r < 2; r++) {
            int row = m0 + tm * 2 + r;
            float4 o;
            o.x = acc[r][0]; o.y = acc[r][1];
            o.z = acc[r][2]; o.w = acc[r][3];
            *(float4*)&hv[row * NH + col] = o;
        }
    }
}

// ---------------------------------------------------------------------------
// Kernel 3: fused arc scores + softmax CE + label head CE.
// One block per (b, group of 8 i-rows) = 256 blocks, 256 threads.
// Scores never leave LDS.
// ---------------------------------------------------------------------------
__global__ __launch_bounds__(256) void score_loss(
    const float* __restrict__ u, const float* __restrict__ hv,
    const float* __restrict__ vroot, const float* __restrict__ W_arc,
    const float* __restrict__ W_lab, const float* __restrict__ b_lab,
    const int* __restrict__ slens, const int* __restrict__ arcs,
    const int* __restrict__ labels, float* __restrict__ accum)
{
    int blk = blockIdx.x;
    int b = blk >> 4;
    int i0 = (blk & 15) * 8;
    int slen = slens[b];
    if (i0 >= slen) return;           // whole 8-row group masked
    int tid = threadIdx.x;

    __shared__ float v_s[32][133];    // k-chunk of v, k-major, padded
    __shared__ float u_s[32][9];      // k-chunk of u rows
    __shared__ float wa_s[NH];
    __shared__ float s_sc[8][132];    // scores, cols 129..131 = -inf pad
    __shared__ float sel_s[8][NH];
    __shared__ float ll_s[8][48];     // label logits, cols 45..47 = -inf pad
    __shared__ float rowce[8];

    wa_s[tid] = W_arc[tid];
    int i_c = tid >> 5;               // compute row 0..7
    int jl  = tid & 31;
    int slot4j = 128 + jl; if (slot4j > 131) slot4j = 131;
    float acc[5] = {0.f, 0.f, 0.f, 0.f, 0.f};
    const float* urow_base = u + (size_t)(b * NL + i0) * NH;

    for (int k0 = 0; k0 < NH; k0 += 32) {
        // stage u rows (coalesced 32-wide per row)
        u_s[tid & 31][tid >> 5] = urow_base[(tid >> 5) * NH + k0 + (tid & 31)];
        // stage v rows 0..128, transposed to k-major
        #pragma unroll
        for (int h = 0; h < 5; h++) {
            int idx = tid + h * 256;
            if (idx < 1032) {
                int j = idx >> 3, kq = (idx & 7) * 4;
                const float* src = (j == 0)
                    ? (vroot + k0 + kq)
                    : (hv + (size_t)(b * NL + j - 1) * NH + k0 + kq);
                float4 t4 = *(const float4*)src;
                v_s[kq + 0][j] = t4.x; v_s[kq + 1][j] = t4.y;
                v_s[kq + 2][j] = t4.z; v_s[kq + 3][j] = t4.w;
            }
        }
        if (tid < 32) {               // zero pad cols 129..132
            v_s[tid][129] = 0.f; v_s[tid][130] = 0.f;
            v_s[tid][131] = 0.f; v_s[tid][132] = 0.f;
        }
        __syncthreads();
        #pragma unroll 8
        for (int kk = 0; kk < 32; kk++) {
            float uv = u_s[kk][i_c];
            float w  = wa_s[k0 + kk];
            acc[0] += fmaxf(uv + v_s[kk][jl      ], 0.f) * w;
            acc[1] += fmaxf(uv + v_s[kk][jl + 32 ], 0.f) * w;
            acc[2] += fmaxf(uv + v_s[kk][jl + 64 ], 0.f) * w;
            acc[3] += fmaxf(uv + v_s[kk][jl + 96 ], 0.f) * w;
            acc[4] += fmaxf(uv + v_s[kk][slot4j  ], 0.f) * w;
        }
        __syncthreads();
    }
    s_sc[i_c][jl      ] = acc[0];
    s_sc[i_c][jl + 32 ] = acc[1];
    s_sc[i_c][jl + 64 ] = acc[2];
    s_sc[i_c][jl + 96 ] = acc[3];
    if (jl == 0) s_sc[i_c][128] = acc[4];
    if (jl >= 1 && jl <= 3) s_sc[i_c][128 + jl] = -INFINITY;
    __syncthreads();

    // ---- arc softmax CE: wave w handles rows 2w, 2w+1 ----
    int w = tid >> 6, lane = tid & 63;
    #pragma unroll
    for (int rr = 0; rr < 2; rr++) {
        int r = w * 2 + rr;
        float x0 = s_sc[r][lane];
        float x1 = s_sc[r][lane + 64];
        float x2 = (lane == 0) ? s_sc[r][128] : -INFINITY;
        float m = fmaxf(fmaxf(x0, x1), x2);
        #pragma unroll
        for (int off = 32; off > 0; off >>= 1)
            m = fmaxf(m, __shfl_xor(m, off));
        float e = expf(x0 - m) + expf(x1 - m)
                + ((lane == 0) ? expf(x2 - m) : 0.f);
        #pragma unroll
        for (int off = 32; off > 0; off >>= 1)
            e += __shfl_xor(e, off);
        if (lane == 0) {
            int row = b * NL + i0 + r;
            rowce[r] = (m + logf(e)) - s_sc[r][arcs[row]];
        }
    }

    // ---- stage sel = relu(u_row + v[arc]) ----
    {
        int i = tid >> 5;
        int row = b * NL + i0 + i;
        int a = arcs[row];
        const float* vr = (a == 0) ? vroot
                        : (hv + (size_t)(b * NL + a - 1) * NH);
        const float* ur = u + (size_t)row * NH;
        int k = (tid & 31) * 8;
        float4 u0 = *(const float4*)&ur[k],     v0 = *(const float4*)&vr[k];
        float4 u1 = *(const float4*)&ur[k + 4], v1 = *(const float4*)&vr[k + 4];
        sel_s[i][k + 0] = fmaxf(u0.x + v0.x, 0.f);
        sel_s[i][k + 1] = fmaxf(u0.y + v0.y, 0.f);
        sel_s[i][k + 2] = fmaxf(u0.z + v0.z, 0.f);
        sel_s[i][k + 3] = fmaxf(u0.w + v0.w, 0.f);
        sel_s[i][k + 4] = fmaxf(u1.x + v1.x, 0.f);
        sel_s[i][k + 5] = fmaxf(u1.y + v1.y, 0.f);
        sel_s[i][k + 6] = fmaxf(u1.z + v1.z, 0.f);
        sel_s[i][k + 7] = fmaxf(u1.w + v1.w, 0.f);
    }
    __syncthreads();

    // ---- label logits: thread (i, t) does tags t and t+32 ----
    {
        int i = tid >> 5, t = tid & 31;
        bool has2 = (t + 32) < NTAGS;
        float lg0 = b_lab[t];
        float lg1 = has2 ? b_lab[t + 32] : 0.f;
        #pragma unroll 4
        for (int k = 0; k < NH; k++) {
            float s = sel_s[i][k];
            lg0 += s * W_lab[k * NTAGS + t];
            if (has2) lg1 += s * W_lab[k * NTAGS + t + 32];
        }
        ll_s[i][t] = lg0;
        if (has2) ll_s[i][t + 32] = lg1;
        if (t >= 13 && t < 16) ll_s[i][t + 32] = -INFINITY;  // pad 45..47
    }
    __syncthreads();

    // ---- label softmax CE + per-row combine ----
    #pragma unroll
    for (int rr = 0; rr < 2; rr++) {
        int r = w * 2 + rr;
        float y = (lane < 48) ? ll_s[r][lane] : -INFINITY;
        float m2 = y;
        #pragma unroll
        for (int off = 32; off > 0; off >>= 1)
            m2 = fmaxf(m2, __shfl_xor(m2, off));
        float e2 = (lane < 48) ? expf(y - m2) : 0.f;
        #pragma unroll
        for (int off = 32; off > 0; off >>= 1)
            e2 += __shfl_xor(e2, off);
        if (lane == 0) {
            int row = b * NL + i0 + r;
            float lab_ce = (m2 + logf(e2)) - ll_s[r][labels[row]];
            bool act = (i0 + r) < slen;
            rowce[r] = act ? (rowce[r] + lab_ce) : 0.f;
        }
    }
    __syncthreads();
    if (tid == 0) {
        float s = 0.f;
        #pragma unroll
        for (int r = 0; r < 8; r++) s += rowce[r];
        atomicAdd(accum, s);
    }
}

// ---------------------------------------------------------------------------
// finalize: out = 0.5 * accum / max(sum(slens), 1)
// ---------------------------------------------------------------------------
__global__ void finalize_kernel(const float* __restrict__ accum,
                                const int* __restrict__ slens,
                                float* __restrict__ out)
{
    if (threadIdx.x == 0) {
        int d = 0;
        #pragma unroll
        for (int b = 0; b < NB; b++) d += slens[b];
        float denom = fmaxf((float)d, 1.f);
        out[0] = 0.5f * accum[0] / denom;
    }
}

extern "C" void kernel_launch(void* const* d_in, const int* in_sizes, int n_in,
                              void* d_out, int out_size, void* d_ws, size_t ws_size,
                              hipStream_t stream) {
    (void)in_sizes; (void)n_in; (void)out_size; (void)ws_size;
    const float* ctx   = (const float*)d_in[0];
    const int*   slens = (const int*)  d_in[1];
    const int*   arcs  = (const int*)  d_in[2];
    const int*   labs  = (const int*)  d_in[3];
    const float* W1    = (const float*)d_in[4];
    const float* b1    = (const float*)d_in[5];
    const float* root  = (const float*)d_in[6];
    const float* Wp    = (const float*)d_in[7];
    const float* bp    = (const float*)d_in[8];
    const float* W_arc = (const float*)d_in[9];
    const float* W_lab = (const float*)d_in[11];
    const float* b_lab = (const float*)d_in[12];
    float* out = (float*)d_out;

    float* ws     = (float*)d_ws;
    float* hidden = ws + HID_OFF;
    float* u      = ws + U_OFF;
    float* hv     = ws + HV_OFF;
    float* vroot  = ws + VROOT_OFF;
    float* accum  = ws + ACC_OFF;

    gemm_hidden<<<dim3(NM / 32, NH / 64), 256, 0, stream>>>(ctx, W1, b1, hidden, accum);
    gemm_uv<<<dim3(65, 8), 256, 0, stream>>>(hidden, Wp, bp, root, u, hv, vroot);
    score_loss<<<NB * 16, 256, 0, stream>>>(u, hv, vroot, W_arc, W_lab, b_lab,
                                            slens, arcs, labs, accum);
    finalize_kernel<<<1, 64, 0, stream>>>(accum, slens, out);
}

// Round 4
// 161.631 us; speedup vs baseline: 1.3813x; 1.3813x over previous
//
#include <hip/hip_runtime.h>
#include <math.h>

// Problem constants
#define NB 16
#define NL 128
#define DIN 512
#define NH 256
#define NTAGS 45
#define NM (NB*NL)          // 2048 rows
#define NJ (NL+1)           // 129 arc columns
#define NJP 132             // padded score row stride

// ws layout (floats)
#define HID_OFF   0
#define U_OFF     (NM*NH)                 // 524288
#define HV_OFF    (U_OFF + NM*NH)         // 1048576
#define VROOT_OFF (HV_OFF + NM*NH)        // 1572864
#define ACC_OFF   (VROOT_OFF + NH)        // 1573120
#define SC_OFF    (ACC_OFF + 4)           // 1573124 (16B aligned)
// scores: 2 partial buffers of NM*NJP each

// ---------------------------------------------------------------------------
// Kernel 1: hidden = relu(C @ W1 + b1)   (2048x512)@(512x256)
// tile 32(M) x 64(N), BK=16, 256 threads, 2x4/thread -> 256 blocks.
// Block (0,0) also zeroes the loss accumulator (ws is poisoned each call).
// ---------------------------------------------------------------------------
__global__ __launch_bounds__(256) void gemm_hidden(
    const float* __restrict__ A,   // 2048 x 512
    const float* __restrict__ W,   // 512 x 256
    const float* __restrict__ bias,// 256
    float* __restrict__ out,       // 2048 x 256
    float* __restrict__ accum)
{
    const int K = DIN, N = NH;
    __shared__ float As[16][34];
    __shared__ float Bs[16][68];
    int m0 = blockIdx.x * 32;
    int n0 = blockIdx.y * 64;
    int tid = threadIdx.x;
    if (blockIdx.x == 0 && blockIdx.y == 0 && tid == 0) accum[0] = 0.f;
    int tm = tid >> 4, tn = tid & 15;
    int lm = tid >> 2, lk = (tid & 3) * 4;
    int bk = tid >> 4, bn = (tid & 15) * 4;
    float acc[2][4] = {{0.f}};

    for (int k0 = 0; k0 < K; k0 += 16) {
        if (tid < 128) {
            float4 a4 = *(const float4*)&A[(m0 + lm) * K + k0 + lk];
            As[lk + 0][lm] = a4.x; As[lk + 1][lm] = a4.y;
            As[lk + 2][lm] = a4.z; As[lk + 3][lm] = a4.w;
        }
        float4 b4 = *(const float4*)&W[(k0 + bk) * N + n0 + bn];
        *(float4*)&Bs[bk][bn] = b4;
        __syncthreads();
        #pragma unroll
        for (int kk = 0; kk < 16; kk++) {
            float2 a2 = *(const float2*)&As[kk][tm * 2];
            float4 bv = *(const float4*)&Bs[kk][tn * 4];
            float ar[2] = {a2.x, a2.y};
            float br[4] = {bv.x, bv.y, bv.z, bv.w};
            #pragma unroll
            for (int r = 0; r < 2; r++)
                #pragma unroll
                for (int c = 0; c < 4; c++)
                    acc[r][c] += ar[r] * br[c];
        }
        __syncthreads();
    }
    int col = n0 + tn * 4;
    float4 bb = *(const float4*)&bias[col];
    #pragma unroll
    for (int r = 0; r < 2; r++) {
        int row = m0 + tm * 2 + r;
        float4 o;
        o.x = fmaxf(acc[r][0] + bb.x, 0.f);
        o.y = fmaxf(acc[r][1] + bb.y, 0.f);
        o.z = fmaxf(acc[r][2] + bb.z, 0.f);
        o.w = fmaxf(acc[r][3] + bb.w, 0.f);
        *(float4*)&out[row * N + col] = o;
    }
}

// ---------------------------------------------------------------------------
// Kernel 2: u = hidden@Wa + bp ; hv = hidden@Wb ; vroot = root@Wb
// GEMM M=2048, N=512, K=256; tile 32x64 -> grid (65, 8); blockIdx.x==64
// computes the root row (k-parallel, 4 partials reduced in LDS).
// ---------------------------------------------------------------------------
__global__ __launch_bounds__(256) void gemm_uv(
    const float* __restrict__ hidden, // 2048 x 256
    const float* __restrict__ Wp,     // 512 x 256
    const float* __restrict__ bp,     // 256
    const float* __restrict__ root,   // 256
    float* __restrict__ u,            // 2048 x 256
    float* __restrict__ hv,           // 2048 x 256
    float* __restrict__ vroot)        // 256
{
    const int K = NH;
    __shared__ float As[16][34];
    __shared__ float Bs[16][68];
    __shared__ float part[4][64];
    int n0 = blockIdx.y * 64;
    int tid = threadIdx.x;

    if (blockIdx.x == 64) {            // root row block
        if (n0 < NH) return;
        int col = (n0 - NH) + (tid & 63);
        int kc = tid >> 6;
        float p = 0.f;
        #pragma unroll 8
        for (int c = kc * 64; c < kc * 64 + 64; c++)
            p += root[c] * Wp[(NH + c) * NH + col];
        part[kc][tid & 63] = p;
        __syncthreads();
        if (tid < 64)
            vroot[(n0 - NH) + tid] = part[0][tid] + part[1][tid]
                                   + part[2][tid] + part[3][tid];
        return;
    }

    int m0 = blockIdx.x * 32;
    bool isU = (n0 < NH);
    int tm = tid >> 4, tn = tid & 15;
    int lm = tid >> 2, lk = (tid & 3) * 4;
    int bk = tid >> 4, bn = (tid & 15) * 4;
    float acc[2][4] = {{0.f}};

    for (int k0 = 0; k0 < K; k0 += 16) {
        if (tid < 128) {
            float4 a4 = *(const float4*)&hidden[(m0 + lm) * K + k0 + lk];
            As[lk + 0][lm] = a4.x; As[lk + 1][lm] = a4.y;
            As[lk + 2][lm] = a4.z; As[lk + 3][lm] = a4.w;
        }
        int c = k0 + bk;
        float4 b4;
        if (isU) b4 = *(const float4*)&Wp[c * NH + n0 + bn];
        else     b4 = *(const float4*)&Wp[(NH + c) * NH + (n0 - NH) + bn];
        *(float4*)&Bs[bk][bn] = b4;
        __syncthreads();
        #pragma unroll
        for (int kk = 0; kk < 16; kk++) {
            float2 a2 = *(const float2*)&As[kk][tm * 2];
            float4 bv = *(const float4*)&Bs[kk][tn * 4];
            float ar[2] = {a2.x, a2.y};
            float br[4] = {bv.x, bv.y, bv.z, bv.w};
            #pragma unroll
            for (int r = 0; r < 2; r++)
                #pragma unroll
                for (int cc = 0; cc < 4; cc++)
                    acc[r][cc] += ar[r] * br[cc];
        }
        __syncthreads();
    }
    if (isU) {
        int col = n0 + tn * 4;
        float4 bb = *(const float4*)&bp[col];
        #pragma unroll
        for (int r = 0; r < 2; r++) {
            int row = m0 + tm * 2 + r;
            float4 o;
            o.x = acc[r][0] + bb.x; o.y = acc[r][1] + bb.y;
            o.z = acc[r][2] + bb.z; o.w = acc[r][3] + bb.w;
            *(float4*)&u[row * NH + col] = o;
        }
    } else {
        int col = (n0 - NH) + tn * 4;
        #pragma unroll
        for (int r = 0; r < 2; r++) {
            int row = m0 + tm * 2 + r;
            float4 o;
            o.x = acc[r][0]; o.y = acc[r][1];
            o.z = acc[r][2]; o.w = acc[r][3];
            *(float4*)&hv[row * NH + col] = o;
        }
    }
}

// ---------------------------------------------------------------------------
// Kernel 3: partial arc scores, k-split x2.
// scores_part[kh][b,i,j] = sum_{k in half kh} relu(u+v)*wa
// grid (16, 4, 10): z = jt + 5*kh. tile 32(i) x 32(j), 2x2/thread.
// 640 blocks -> ~2.5 blocks/CU.
// ---------------------------------------------------------------------------
__global__ __launch_bounds__(256) void arc_scores_kernel(
    const float* __restrict__ u, const float* __restrict__ hv,
    const float* __restrict__ vroot, const float* __restrict__ W_arc,
    float* __restrict__ scores)   // 2 x NM x NJP
{
    int b = blockIdx.x;
    int i0 = blockIdx.y * 32;
    int jt = blockIdx.z % 5, kh = blockIdx.z / 5;
    int j0 = jt * 32;
    int kbase = kh * 128;
    int tid = threadIdx.x;
    __shared__ float us[64][33];
    __shared__ float vs[64][33];
    __shared__ float wa[NH];
    wa[tid] = W_arc[tid];

    int tx = tid & 15, ty = tid >> 4;   // tx: 2 j-cols, ty: 2 i-rows
    float acc[2][2] = {{0.f}};

    for (int k0 = kbase; k0 < kbase + 128; k0 += 64) {
        #pragma unroll
        for (int h = 0; h < 2; h++) {
            int idx = tid + h * 256;       // 0..511
            int row = idx >> 4;            // 0..31
            int kq  = (idx & 15) * 4;      // 0..60
            float4 a4 = *(const float4*)&u[(size_t)(b * NL + i0 + row) * NH + k0 + kq];
            us[kq + 0][row] = a4.x; us[kq + 1][row] = a4.y;
            us[kq + 2][row] = a4.z; us[kq + 3][row] = a4.w;
            int j = j0 + row; if (j > 128) j = 128;
            const float* src = (j == 0) ? (vroot + k0 + kq)
                             : (hv + (size_t)(b * NL + j - 1) * NH + k0 + kq);
            float4 b4 = *(const float4*)src;
            vs[kq + 0][row] = b4.x; vs[kq + 1][row] = b4.y;
            vs[kq + 2][row] = b4.z; vs[kq + 3][row] = b4.w;
        }
        __syncthreads();
        #pragma unroll 8
        for (int kk = 0; kk < 64; kk++) {
            float w  = wa[k0 - kbase + kk + kbase]; // = wa[k0+kk]
            float u0 = us[kk][ty * 2], u1 = us[kk][ty * 2 + 1];
            float v0 = vs[kk][tx * 2], v1 = vs[kk][tx * 2 + 1];
            acc[0][0] += fmaxf(u0 + v0, 0.f) * w;
            acc[0][1] += fmaxf(u0 + v1, 0.f) * w;
            acc[1][0] += fmaxf(u1 + v0, 0.f) * w;
            acc[1][1] += fmaxf(u1 + v1, 0.f) * w;
        }
        __syncthreads();
    }
    float* dst = scores + (size_t)kh * (NM * NJP);
    #pragma unroll
    for (int r = 0; r < 2; r++) {
        #pragma unroll
        for (int c = 0; c < 2; c++) {
            int j = j0 + tx * 2 + c;
            if (j < NJP)
                dst[(size_t)(b * NL + i0 + ty * 2 + r) * NJP + j] = acc[r][c];
        }
    }
}

// ---------------------------------------------------------------------------
// Kernel 4: loss. 4 rows per block -> 512 blocks, 256 threads.
// Wave w owns row r0+w: arc softmax CE from the two score partials,
// label head CE on sel = relu(u_row + v[arc]). One atomicAdd per block.
// ---------------------------------------------------------------------------
__global__ __launch_bounds__(256) void loss_kernel(
    const float* __restrict__ scores, const float* __restrict__ u,
    const float* __restrict__ hv, const float* __restrict__ vroot,
    const float* __restrict__ W_lab, const float* __restrict__ b_lab,
    const int* __restrict__ slens, const int* __restrict__ arcs,
    const int* __restrict__ labels, float* __restrict__ accum)
{
    int r0 = blockIdx.x * 4;
    int b = r0 >> 7;
    int i_base = r0 & 127;
    int slen = slens[b];
    if (i_base >= slen) return;   // whole group masked
    int tid = threadIdx.x;
    int w = tid >> 6, lane = tid & 63;

    const float* sc0 = scores;
    const float* sc1 = scores + (size_t)NM * NJP;

    __shared__ float sel_s[NH][5];   // stride 5: conflict-free both phases
    __shared__ float ll_s[4][48];
    __shared__ float ce_s[4];
    __shared__ int   arc_sh[4];

    // ---- arc softmax CE: wave w -> row r0+w ----
    {
        int row = r0 + w;
        const float* p0 = sc0 + (size_t)row * NJP;
        const float* p1 = sc1 + (size_t)row * NJP;
        float x0 = p0[lane] + p1[lane];
        float x1 = p0[lane + 64] + p1[lane + 64];
        bool l0 = (lane == 0);
        float x2 = l0 ? (p0[128] + p1[128]) : -INFINITY;
        float m = fmaxf(fmaxf(x0, x1), x2);
        #pragma unroll
        for (int off = 32; off > 0; off >>= 1)
            m = fmaxf(m, __shfl_xor(m, off));
        float e = expf(x0 - m) + expf(x1 - m) + (l0 ? expf(x2 - m) : 0.f);
        #pragma unroll
        for (int off = 32; off > 0; off >>= 1)
            e += __shfl_xor(e, off);
        if (l0) {
            int a = arcs[row];
            arc_sh[w] = a;
            ce_s[w] = (m + logf(e)) - (p0[a] + p1[a]);
        }
    }
    __syncthreads();

    // ---- sel staging: thread = k, loops 4 rows; LDS stride 5 ----
    {
        int k = tid;
        #pragma unroll
        for (int r = 0; r < 4; r++) {
            int a = arc_sh[r];
            const float* vr = (a == 0) ? vroot
                            : (hv + (size_t)(b * NL + a - 1) * NH);
            sel_s[k][r] = fmaxf(u[(size_t)(r0 + r) * NH + k] + vr[k], 0.f);
        }
    }
    __syncthreads();

    // ---- label logits: threads 0..179 -> (row = tid/45, tag = tid%45) ----
    if (tid < 180) {
        int r = tid / 45, t = tid - r * 45;
        float lg = b_lab[t];
        #pragma unroll 8
        for (int k = 0; k < NH; k++)
            lg += sel_s[k][r] * W_lab[k * NTAGS + t];
        ll_s[r][t] = lg;
    } else if (tid < 192) {
        int q = tid - 180;           // 0..11 -> pad cols 45..47
        ll_s[q / 3][45 + q % 3] = -INFINITY;
    }
    __syncthreads();

    // ---- label softmax CE + mask + combine ----
    {
        int row = r0 + w;
        float y = (lane < 48) ? ll_s[w][lane] : -INFINITY;
        float m2 = y;
        #pragma unroll
        for (int off = 32; off > 0; off >>= 1)
            m2 = fmaxf(m2, __shfl_xor(m2, off));
        float e2 = (lane < 48) ? expf(y - m2) : 0.f;
        #pragma unroll
        for (int off = 32; off > 0; off >>= 1)
            e2 += __shfl_xor(e2, off);
        if (lane == 0) {
            float lab_ce = (m2 + logf(e2)) - ll_s[w][labels[row]];
            bool act = (i_base + w) < slen;
            ce_s[w] = act ? (ce_s[w] + lab_ce) : 0.f;
        }
    }
    __syncthreads();
    if (tid == 0)
        atomicAdd(accum, ce_s[0] + ce_s[1] + ce_s[2] + ce_s[3]);
}

// ---------------------------------------------------------------------------
// finalize: out = 0.5 * accum / max(sum(slens), 1)
// ---------------------------------------------------------------------------
__global__ void finalize_kernel(const float* __restrict__ accum,
                                const int* __restrict__ slens,
                                float* __restrict__ out)
{
    if (threadIdx.x == 0) {
        int d = 0;
        #pragma unroll
        for (int b = 0; b < NB; b++) d += slens[b];
        float denom = fmaxf((float)d, 1.f);
        out[0] = 0.5f * accum[0] / denom;
    }
}

extern "C" void kernel_launch(void* const* d_in, const int* in_sizes, int n_in,
                              void* d_out, int out_size, void* d_ws, size_t ws_size,
                              hipStream_t stream) {
    (void)in_sizes; (void)n_in; (void)out_size; (void)ws_size;
    const float* ctx   = (const float*)d_in[0];
    const int*   slens = (const int*)  d_in[1];
    const int*   arcs  = (const int*)  d_in[2];
    const int*   labs  = (const int*)  d_in[3];
    const float* W1    = (const float*)d_in[4];
    const float* b1    = (const float*)d_in[5];
    const float* root  = (const float*)d_in[6];
    const float* Wp    = (const float*)d_in[7];
    const float* bp    = (const float*)d_in[8];
    const float* W_arc = (const float*)d_in[9];
    const float* W_lab = (const float*)d_in[11];
    const float* b_lab = (const float*)d_in[12];
    float* out = (float*)d_out;

    float* ws     = (float*)d_ws;
    float* hidden = ws + HID_OFF;
    float* u      = ws + U_OFF;
    float* hv     = ws + HV_OFF;
    float* vroot  = ws + VROOT_OFF;
    float* accum  = ws + ACC_OFF;
    float* scores = ws + SC_OFF;

    gemm_hidden<<<dim3(NM / 32, NH / 64), 256, 0, stream>>>(ctx, W1, b1, hidden, accum);
    gemm_uv<<<dim3(65, 8), 256, 0, stream>>>(hidden, Wp, bp, root, u, hv, vroot);
    arc_scores_kernel<<<dim3(NB, 4, 10), 256, 0, stream>>>(u, hv, vroot, W_arc, scores);
    loss_kernel<<<NM / 4, 256, 0, stream>>>(scores, u, hv, vroot, W_lab, b_lab,
                                            slens, arcs, labs, accum);
    finalize_kernel<<<1, 64, 0, stream>>>(accum, slens, out);
}